// Round 13
// baseline (2349.071 us; speedup 1.0000x reference)
//
#include <hip/hip_runtime.h>
#include <hip/hip_bf16.h>
#include <cstdint>
#include <cstddef>
#include <type_traits>

// KAN GLU expert: h = kan(x;w1) * kan(x;w2); out = kan(h;w3)
// kan(x;W) == [silu(x_i), B0..B7(x_i)]_i @ [base_w | spline_w]^T
// -> bf16 MFMA GEMMs with K expanded 9x.
//
// GEMM (R13): 256x256 block, 8 waves (2Mx4N), wave tile 128x64, BK=64.
// A-operand loaded DIRECTLY from global into registers (fragment rows are
// 16B-contiguous; 4x wc-redundancy served by L1/L2) -- only B goes through
// LDS (ring-2 32KB slots, swizzle gp = gl ^ (row&7), measured conflict-free).
// One vmcnt(0)+lgkm+barrier per K-64 tile. Cuts LDS reads 24->8 per
// wave-tile (serial-sum model: -1536 cy/tile).
// Fused path: GEMM1 epilogue does GLU (interleaved W12 rows, shfl_xor)
// + KAN features -> A3 directly (no H). GEMM2 single dispatch split-K=4.

#define D_MODEL 1024
#define D_FF    4096
#define NTOK    4096
#define NC      9
#define K1      (D_MODEL * NC)  // 9216
#define K3      (D_FF * NC)     // 36864
#define SPLITK2 16              // fallback chunked GEMM2
#define SPLITKF 4               // fused full GEMM2
#define CHUNK   1024
#define SLOT    32768           // ring-2 slot: B 32KB

typedef __attribute__((ext_vector_type(8))) short bf16x8;
typedef __attribute__((ext_vector_type(4))) float f32x4;

__device__ __forceinline__ unsigned short bf16b(float f) {
  __hip_bfloat16 h = __float2bfloat16(f);
  return __builtin_bit_cast(unsigned short, h);
}

// ---------------------------------------------------------------------------
// silu + 8 cubic B-spline bases on uniform grid t_m = 0.4*m - 2.2
// ---------------------------------------------------------------------------
__device__ __forceinline__ void kan_feat_u(float x, unsigned short* dst) {
  float s = x / (1.0f + __expf(-x));
  float B[11];
#pragma unroll
  for (int j = 0; j < 11; ++j) {
    float gj = -2.2f + 0.4f * j;
    B[j] = (x >= gj && x < gj + 0.4f) ? 1.0f : 0.0f;
  }
#pragma unroll
  for (int p = 1; p <= 3; ++p) {
    float inv = 1.0f / (0.4f * p);
#pragma unroll
    for (int i = 0; i + p < 11; ++i) {
      float gi = -2.2f + 0.4f * i;
      B[i] = (x - gi) * inv * B[i] + ((gi + 0.4f + 0.4f * p) - x) * inv * B[i + 1];
    }
  }
  dst[0] = bf16b(s);
#pragma unroll
  for (int c = 0; c < 8; ++c) dst[1 + c] = bf16b(B[c]);
}

// ---------------------------------------------------------------------------
// Pack two adjacent input-features per thread -> 9 dword stores.
// dst row = o*rowMul + rowBase (rowMul=2 interleaves two layers).
// ---------------------------------------------------------------------------
__global__ void pack_kan_w(const float* __restrict__ bw, const float* __restrict__ sw,
                           __hip_bfloat16* __restrict__ W, int K, int inShift,
                           int rowMul, int rowBase, size_t totalPairs) {
  size_t t = (size_t)blockIdx.x * blockDim.x + threadIdx.x;
  if (t >= totalPairs) return;
  size_t o = t >> (inShift - 1);
  size_t ip = (t & (((size_t)1 << (inShift - 1)) - 1)) * 2;
  size_t e0 = (o << inShift) + ip;
  float2 b = *(const float2*)(bw + e0);
  const float4* sp = (const float4*)(sw + e0 * 8);
  float4 s0 = sp[0], s1 = sp[1], s2 = sp[2], s3 = sp[3];
  unsigned short h[18];
  h[0] = bf16b(b.x);
  h[1] = bf16b(s0.x); h[2] = bf16b(s0.y); h[3] = bf16b(s0.z); h[4] = bf16b(s0.w);
  h[5] = bf16b(s1.x); h[6] = bf16b(s1.y); h[7] = bf16b(s1.z); h[8] = bf16b(s1.w);
  h[9] = bf16b(b.y);
  h[10] = bf16b(s2.x); h[11] = bf16b(s2.y); h[12] = bf16b(s2.z); h[13] = bf16b(s2.w);
  h[14] = bf16b(s3.x); h[15] = bf16b(s3.y); h[16] = bf16b(s3.z); h[17] = bf16b(s3.w);
  uint32_t* dst = (uint32_t*)(W + (o * rowMul + rowBase) * (size_t)K + ip * NC);
#pragma unroll
  for (int k = 0; k < 9; ++k) dst[k] = (uint32_t)h[2 * k] | ((uint32_t)h[2 * k + 1] << 16);
}

// A1 from x; two elements per thread
__global__ void build_a1(const float* __restrict__ x, __hip_bfloat16* __restrict__ A1) {
  size_t t = (size_t)blockIdx.x * blockDim.x + threadIdx.x;
  if (t >= (size_t)NTOK * D_MODEL / 2) return;
  size_t n = t >> 9;
  size_t ip = (t & 511) * 2;
  float2 xv = *(const float2*)(x + n * D_MODEL + ip);
  unsigned short h[18];
  kan_feat_u(xv.x, h);
  kan_feat_u(xv.y, h + 9);
  uint32_t* dst = (uint32_t*)(A1 + n * (size_t)K1 + ip * NC);
#pragma unroll
  for (int k = 0; k < 9; ++k) dst[k] = (uint32_t)h[2 * k] | ((uint32_t)h[2 * k + 1] << 16);
}

// fallback only: h = Hc[:, :4096] * Hc[:, 4096:]; two j per thread
template <typename HT>
__global__ void glu_a3(const HT* __restrict__ Hc, __hip_bfloat16* __restrict__ A3c) {
  size_t t = (size_t)blockIdx.x * blockDim.x + threadIdx.x;
  if (t >= (size_t)CHUNK * D_FF / 2) return;
  size_t n = t >> 11;
  size_t jp = (t & 2047) * 2;
  float a0, a1, c0, c1;
  if constexpr (std::is_same<HT, float>::value) {
    float2 u = *(const float2*)(Hc + n * 8192 + jp);
    float2 v = *(const float2*)(Hc + n * 8192 + 4096 + jp);
    a0 = u.x; a1 = u.y; c0 = v.x; c1 = v.y;
  } else {
    a0 = __bfloat162float(Hc[n * 8192 + jp]);
    a1 = __bfloat162float(Hc[n * 8192 + jp + 1]);
    c0 = __bfloat162float(Hc[n * 8192 + 4096 + jp]);
    c1 = __bfloat162float(Hc[n * 8192 + 4096 + jp + 1]);
  }
  unsigned short h[18];
  kan_feat_u(a0 * c0, h);
  kan_feat_u(a1 * c1, h + 9);
  uint32_t* dst = (uint32_t*)(A3c + n * (size_t)K3 + jp * NC);
#pragma unroll
  for (int k = 0; k < 9; ++k) dst[k] = (uint32_t)h[2 * k] | ((uint32_t)h[2 * k + 1] << 16);
}

// ---------------------------------------------------------------------------
// 256x256 bf16 GEMM, BK=64, ring-2 (B only). C = A (M x K) * Bw^T (N x K).
// B staging per tile: 4 sites x (512thr x 16B) = 32KB. Site covers 64 rows.
// Per-lane: row = wid*8 + (lane>>3), source k-group (lane&7)^(lane>>3);
// LDS dest linear => physical gp = gl ^ (row&7).
// A fragments loaded directly from global (16B contiguous per lane).
// ---------------------------------------------------------------------------
#define STAGE_B(Ts)                                                                      \
  {                                                                                      \
    const int _sl = ((Ts) & 1) * SLOT;                                                   \
    const size_t _ko = (size_t)(Ts) * 128;                                               \
    _Pragma("unroll") for (int _st = 0; _st < 4; ++_st) {                                \
      __builtin_amdgcn_global_load_lds(                                                  \
          (const __attribute__((address_space(1))) void*)(gB0 + _st * strideK + _ko),    \
          (__attribute__((address_space(3))) void*)(lds_raw + _sl + _st * 8192 + dW),    \
          16, 0, 0);                                                                     \
    }                                                                                    \
  }

template <typename CT, bool FUSE>
__global__ __launch_bounds__(512, 2) void gemm256(
    const __hip_bfloat16* __restrict__ A, const __hip_bfloat16* __restrict__ Bw,
    CT* __restrict__ Cp, int N, int K, int kLen,
    __hip_bfloat16* __restrict__ A3out) {
  __shared__ __align__(16) char lds_raw[131072];  // ring-2 64KB; epilogue gbuf 128KB

  const int tid = threadIdx.x;
  const int wid = tid >> 6, lane = tid & 63;
  const int wr = wid >> 2, wc = wid & 3;  // 2M x 4N waves, 128x64 tiles

  // bijective XCD swizzle (T1); all grids have nwg % 8 == 0
  const int nwg = gridDim.x * gridDim.y;
  const int orig = blockIdx.y * gridDim.x + blockIdx.x;
  const int q = nwg >> 3, r = nwg & 7;
  const int xcd = orig & 7, lid = orig >> 3;
  const int wg = (xcd < r ? xcd * (q + 1) : r * (q + 1) + (xcd - r) * q) + lid;
  const int bx = wg % gridDim.x, by = wg / gridDim.x;

  const size_t brow = (size_t)by * 256;
  const size_t bcol = (size_t)bx * 256;
  const int kStart = (int)blockIdx.z * kLen;
  const int NT = kLen / 64;

  // B staging addressing
  const int kbx = (lane & 7) ^ (lane >> 3);  // source 16B-group within 128B row
  const int rsub = lane >> 3;                // row within 8-row wave stripe
  const size_t strideK = (size_t)K * 128;    // 64 rows * K * 2B
  const char* gB0 = (const char*)Bw +
      ((bcol + (size_t)(wid * 8 + rsub)) * (size_t)K + kStart + kbx * 8) * 2;
  const int dW = wid * 1024;

  // B frag read offsets (measured conflict-free pattern, R10/R12)
  const int gx0 = (((lane >> 4) ^ (lane & 7))) * 16;
  const int gx1 = ((((lane >> 4) + 4) ^ (lane & 7))) * 16;
  const int brw = (wc * 64 + (lane & 15)) * 128;

  // A direct-load base: row = brow + wr*128 + mf*16 + (lane&15), k-base (lane>>4)*8
  const __hip_bfloat16* aBase =
      A + (brow + (size_t)(wr * 128 + (lane & 15))) * (size_t)K + kStart + (lane >> 4) * 8;

  f32x4 acc[8][4] = {};

  // prologue: stage B tile 0, drain, barrier
  STAGE_B(0);
  asm volatile("s_waitcnt vmcnt(0)" ::: "memory");
  __builtin_amdgcn_s_barrier();

  for (int T = 0; T < NT; ++T) {
    if (T + 1 < NT) STAGE_B(T + 1);

    const int sl = (T & 1) * SLOT;
    const __hip_bfloat16* aT = aBase + (size_t)T * 64;
    bf16x8 af0[8], af1[8], bfr[4];
#pragma unroll
    for (int mf = 0; mf < 8; ++mf)
      af0[mf] = *(const bf16x8*)(aT + (size_t)mf * 16 * K);
#pragma unroll
    for (int mf = 0; mf < 8; ++mf)
      af1[mf] = *(const bf16x8*)(aT + (size_t)mf * 16 * K + 32);
    // ---- K-half 0
#pragma unroll
    for (int nf = 0; nf < 4; ++nf)
      bfr[nf] = *(const bf16x8*)(lds_raw + sl + brw + nf * 2048 + gx0);
    __builtin_amdgcn_s_setprio(1);
#pragma unroll
    for (int mf = 0; mf < 8; ++mf)
#pragma unroll
      for (int nf = 0; nf < 4; ++nf)
        acc[mf][nf] =
            __builtin_amdgcn_mfma_f32_16x16x32_bf16(af0[mf], bfr[nf], acc[mf][nf], 0, 0, 0);
    __builtin_amdgcn_s_setprio(0);
    // ---- K-half 1
#pragma unroll
    for (int nf = 0; nf < 4; ++nf)
      bfr[nf] = *(const bf16x8*)(lds_raw + sl + brw + nf * 2048 + gx1);
    __builtin_amdgcn_s_setprio(1);
#pragma unroll
    for (int mf = 0; mf < 8; ++mf)
#pragma unroll
      for (int nf = 0; nf < 4; ++nf)
        acc[mf][nf] =
            __builtin_amdgcn_mfma_f32_16x16x32_bf16(af1[mf], bfr[nf], acc[mf][nf], 0, 0, 0);
    __builtin_amdgcn_s_setprio(0);

    // one drain + barrier per K-64 tile
    asm volatile("s_waitcnt vmcnt(0)" ::: "memory");
    asm volatile("s_waitcnt lgkmcnt(0)" ::: "memory");
    __builtin_amdgcn_s_barrier();
  }

  if constexpr (FUSE) {
    // ---- GLU + KAN-feature epilogue -> A3 (interleaved cols: 2p=w1, 2p+1=w2)
    float* gbuf = (float*)lds_raw;  // 16 slices x 16 rows x 128 pairs f32 = 128KB
#pragma unroll
    for (int mf = 0; mf < 8; ++mf) {
      const int s = wr * 8 + mf;
#pragma unroll
      for (int nf = 0; nf < 4; ++nf) {
#pragma unroll
        for (int rr = 0; rr < 4; ++rr) {
          float v = acc[mf][nf][rr];
          float w = __shfl_xor(v, 1, 64);
          if (!(lane & 1)) {
            const int r4 = (lane >> 4) * 4 + rr;
            const int ploc = wc * 32 + nf * 8 + ((lane & 14) >> 1);
            gbuf[s * 2048 + r4 * 128 + ploc] = v * w;
          }
        }
      }
    }
    __builtin_amdgcn_s_barrier();
    const int p2 = tid & 63;   // pair-pair index (handles pairs 2p2, 2p2+1)
    const int rb = tid >> 6;   // base row
    for (int k = 0; k < 32; ++k) {
      const int rr_ = rb + 8 * k;  // 0..255
      const int s = rr_ >> 4, rl = rr_ & 15;
      float g0 = gbuf[s * 2048 + rl * 128 + 2 * p2];
      float g1 = gbuf[s * 2048 + rl * 128 + 2 * p2 + 1];
      unsigned short h[18];
      kan_feat_u(g0, h);
      kan_feat_u(g1, h + 9);
      const size_t n = brow + rr_;
      const size_t pg = (bcol >> 1) + 2 * p2;
      uint32_t* dst = (uint32_t*)(A3out + n * (size_t)K3 + pg * NC);
#pragma unroll
      for (int qq = 0; qq < 9; ++qq)
        dst[qq] = (uint32_t)h[2 * qq] | ((uint32_t)h[2 * qq + 1] << 16);
    }
  } else {
    // plain epilogue: C/D layout col=lane&15, row=(lane>>4)*4+r
#pragma unroll
    for (int mf = 0; mf < 8; ++mf)
#pragma unroll
      for (int nf = 0; nf < 4; ++nf) {
        const size_t r0 = brow + wr * 128 + mf * 16 + (lane >> 4) * 4;
        const size_t c0 = bcol + wc * 64 + nf * 16 + (lane & 15);
        const size_t M = (size_t)gridDim.y * 256;
        CT* C = Cp + (size_t)blockIdx.z * M * (size_t)N;
#pragma unroll
        for (int rr = 0; rr < 4; ++rr) {
          float v = acc[mf][nf][rr];
          if constexpr (std::is_same<CT, float>::value)
            C[(r0 + rr) * (size_t)N + c0] = v;
          else
            C[(r0 + rr) * (size_t)N + c0] = __float2bfloat16(v);
        }
      }
  }
}

// sum nslice split-K partials (float4-vectorized)
__global__ void reduceK(const float* __restrict__ P, float* __restrict__ out,
                        size_t quarter, int nslice) {
  size_t t = (size_t)blockIdx.x * blockDim.x + threadIdx.x;
  if (t >= quarter) return;
  const float4* p = (const float4*)P;
  float4 a = p[t];
  for (int s = 1; s < nslice; ++s) {
    float4 b = p[(size_t)s * quarter + t];
    a.x += b.x; a.y += b.y; a.z += b.z; a.w += b.w;
  }
  ((float4*)out)[t] = a;
}

// ---------------------------------------------------------------------------
extern "C" void kernel_launch(void* const* d_in, const int* in_sizes, int n_in,
                              void* d_out, int out_size, void* d_ws, size_t ws_size,
                              hipStream_t stream) {
  const float* x   = (const float*)d_in[0];
  const float* bw1 = (const float*)d_in[1];
  const float* sw1 = (const float*)d_in[2];
  const float* bw2 = (const float*)d_in[3];
  const float* sw2 = (const float*)d_in[4];
  const float* bw3 = (const float*)d_in[5];
  const float* sw3 = (const float*)d_in[6];
  float* out = (float*)d_out;
  char* ws = (char*)d_ws;

  const size_t W12_B  = (size_t)8192 * K1 * 2;   // 150,994,944
  const size_t A1_B   = (size_t)NTOK * K1 * 2;   //  75,497,472
  const size_t A3F_B  = (size_t)NTOK * K3 * 2;   // 301,989,888
  const size_t A3C_B  = (size_t)CHUNK * K3 * 2;  //  75,497,472
  const size_t HF32_B = (size_t)NTOK * 8192 * 4; // 134,217,728

  const bool fused = ws_size >= W12_B + A1_B + A3F_B;  // 528,482,304
  const bool hF32  = ws_size >= W12_B + A1_B + HF32_B; // 360,710,144 (fallback)

  __hip_bfloat16* W12 = (__hip_bfloat16*)(ws);
  __hip_bfloat16* A1  = (__hip_bfloat16*)(ws + W12_B);
  __hip_bfloat16* W3  = A1;  // A1 dead after GEMM1

  size_t pairs12 = (size_t)D_FF * D_MODEL / 2;
  int blocks12 = (int)((pairs12 + 255) / 256);
  size_t pairs3 = (size_t)D_MODEL * D_FF / 2;
  int blocks3 = (int)((pairs3 + 255) / 256);
  size_t pairsA1 = (size_t)NTOK * D_MODEL / 2;

  if (fused) {
    __hip_bfloat16* A3f = (__hip_bfloat16*)(ws + W12_B + A1_B);
    float*          Par = (float*)(ws);  // reuses W12 region after GEMM1

    pack_kan_w<<<blocks12, 256, 0, stream>>>(bw1, sw1, W12, K1, 10, 2, 0, pairs12);
    pack_kan_w<<<blocks12, 256, 0, stream>>>(bw2, sw2, W12, K1, 10, 2, 1, pairs12);
    build_a1<<<(int)((pairsA1 + 255) / 256), 256, 0, stream>>>(x, A1);
    gemm256<float, true><<<dim3(8192 / 256, NTOK / 256, 1), 512, 0, stream>>>(
        A1, W12, nullptr, 8192, K1, K1, A3f);
    pack_kan_w<<<blocks3, 256, 0, stream>>>(bw3, sw3, W3, K3, 12, 1, 0, pairs3);
    gemm256<float, false><<<dim3(D_MODEL / 256, NTOK / 256, SPLITKF), 512, 0, stream>>>(
        A3f, W3, Par, D_MODEL, K3, K3 / SPLITKF, nullptr);
    size_t quarter = (size_t)NTOK * D_MODEL / 4;
    reduceK<<<(int)((quarter + 255) / 256), 256, 0, stream>>>(Par, out, quarter, SPLITKF);
  } else {
    void*           Hv  = (void*)(ws + W12_B + A1_B);
    __hip_bfloat16* A3c = (__hip_bfloat16*)(ws);        // W12 dead after GEMM1
    float*          Par = (float*)(ws + A3C_B);

    pack_kan_w<<<blocks12, 256, 0, stream>>>(bw1, sw1, W12, K1, 10, 1, 0, pairs12);
    pack_kan_w<<<blocks12, 256, 0, stream>>>(bw2, sw2, W12, K1, 10, 1, 4096, pairs12);
    build_a1<<<(int)((pairsA1 + 255) / 256), 256, 0, stream>>>(x, A1);
    if (hF32)
      gemm256<float, false><<<dim3(8192 / 256, NTOK / 256, 1), 512, 0, stream>>>(
          A1, W12, (float*)Hv, 8192, K1, K1, nullptr);
    else
      gemm256<__hip_bfloat16, false><<<dim3(8192 / 256, NTOK / 256, 1), 512, 0, stream>>>(
          A1, W12, (__hip_bfloat16*)Hv, 8192, K1, K1, nullptr);
    pack_kan_w<<<blocks3, 256, 0, stream>>>(bw3, sw3, W3, K3, 12, 1, 0, pairs3);
    for (int c = 0; c < NTOK / CHUNK; ++c) {
      size_t pairsG = (size_t)CHUNK * D_FF / 2;
      int blocksG = (int)((pairsG + 255) / 256);
      if (hF32)
        glu_a3<float><<<blocksG, 256, 0, stream>>>(
            (const float*)Hv + (size_t)c * CHUNK * 8192, A3c);
      else
        glu_a3<__hip_bfloat16><<<blocksG, 256, 0, stream>>>(
            (const __hip_bfloat16*)Hv + (size_t)c * CHUNK * 8192, A3c);
      gemm256<float, false><<<dim3(D_MODEL / 256, CHUNK / 256, SPLITK2), 512, 0, stream>>>(
          A3c, W3, Par, D_MODEL, K3, K3 / SPLITK2, nullptr);
      size_t quarter = (size_t)CHUNK * D_MODEL / 4;
      reduceK<<<(int)((quarter + 255) / 256), 256, 0, stream>>>(
          Par, out + (size_t)c * CHUNK * D_MODEL, quarter, SPLITK2);
    }
  }
}

// Round 14
// 1037.597 us; speedup vs baseline: 2.2640x; 2.2640x over previous
//
#include <hip/hip_runtime.h>
#include <hip/hip_bf16.h>
#include <cstdint>
#include <cstddef>
#include <type_traits>

// KAN GLU expert: h = kan(x;w1) * kan(x;w2); out = kan(h;w3)
// kan(x;W) == [silu(x_i), B0..B7(x_i)]_i @ [base_w | spline_w]^T
// -> bf16 MFMA GEMMs with K expanded 9x.
//
// GEMM (R14 = proven R12/R10): 256x256 block, 8 waves (2Mx4N), wave tile
// 128x64, BK=64, ring-2 LDS slots of 64KB (128KB total), 16x16x32 MFMA,
// ONE vmcnt(0)+barrier per K-64 tile (stage issued a full tile ahead).
// 128B LDS rows; swizzle: physical 16B-group gp = gl ^ (row&7), staged via
// pre-swizzled global source; read pattern measured conflict-free.
// Fused path: GEMM1 epilogue does GLU (interleaved W12 rows, shfl_xor)
// + KAN features -> A3 directly (no H). GEMM2 single dispatch split-K=4.

#define D_MODEL 1024
#define D_FF    4096
#define NTOK    4096
#define NC      9
#define K1      (D_MODEL * NC)  // 9216
#define K3      (D_FF * NC)     // 36864
#define SPLITK2 16              // fallback chunked GEMM2
#define SPLITKF 4               // fused full GEMM2
#define CHUNK   1024
#define SLOT    65536           // ring-2 slot: A 32KB + B 32KB

typedef __attribute__((ext_vector_type(8))) short bf16x8;
typedef __attribute__((ext_vector_type(4))) float f32x4;

__device__ __forceinline__ unsigned short bf16b(float f) {
  __hip_bfloat16 h = __float2bfloat16(f);
  return __builtin_bit_cast(unsigned short, h);
}

// ---------------------------------------------------------------------------
// silu + 8 cubic B-spline bases on uniform grid t_m = 0.4*m - 2.2
// ---------------------------------------------------------------------------
__device__ __forceinline__ void kan_feat_u(float x, unsigned short* dst) {
  float s = x / (1.0f + __expf(-x));
  float B[11];
#pragma unroll
  for (int j = 0; j < 11; ++j) {
    float gj = -2.2f + 0.4f * j;
    B[j] = (x >= gj && x < gj + 0.4f) ? 1.0f : 0.0f;
  }
#pragma unroll
  for (int p = 1; p <= 3; ++p) {
    float inv = 1.0f / (0.4f * p);
#pragma unroll
    for (int i = 0; i + p < 11; ++i) {
      float gi = -2.2f + 0.4f * i;
      B[i] = (x - gi) * inv * B[i] + ((gi + 0.4f + 0.4f * p) - x) * inv * B[i + 1];
    }
  }
  dst[0] = bf16b(s);
#pragma unroll
  for (int c = 0; c < 8; ++c) dst[1 + c] = bf16b(B[c]);
}

// ---------------------------------------------------------------------------
// Pack two adjacent input-features per thread -> 9 dword stores.
// dst row = o*rowMul + rowBase (rowMul=2 interleaves two layers).
// ---------------------------------------------------------------------------
__global__ void pack_kan_w(const float* __restrict__ bw, const float* __restrict__ sw,
                           __hip_bfloat16* __restrict__ W, int K, int inShift,
                           int rowMul, int rowBase, size_t totalPairs) {
  size_t t = (size_t)blockIdx.x * blockDim.x + threadIdx.x;
  if (t >= totalPairs) return;
  size_t o = t >> (inShift - 1);
  size_t ip = (t & (((size_t)1 << (inShift - 1)) - 1)) * 2;
  size_t e0 = (o << inShift) + ip;
  float2 b = *(const float2*)(bw + e0);
  const float4* sp = (const float4*)(sw + e0 * 8);
  float4 s0 = sp[0], s1 = sp[1], s2 = sp[2], s3 = sp[3];
  unsigned short h[18];
  h[0] = bf16b(b.x);
  h[1] = bf16b(s0.x); h[2] = bf16b(s0.y); h[3] = bf16b(s0.z); h[4] = bf16b(s0.w);
  h[5] = bf16b(s1.x); h[6] = bf16b(s1.y); h[7] = bf16b(s1.z); h[8] = bf16b(s1.w);
  h[9] = bf16b(b.y);
  h[10] = bf16b(s2.x); h[11] = bf16b(s2.y); h[12] = bf16b(s2.z); h[13] = bf16b(s2.w);
  h[14] = bf16b(s3.x); h[15] = bf16b(s3.y); h[16] = bf16b(s3.z); h[17] = bf16b(s3.w);
  uint32_t* dst = (uint32_t*)(W + (o * rowMul + rowBase) * (size_t)K + ip * NC);
#pragma unroll
  for (int k = 0; k < 9; ++k) dst[k] = (uint32_t)h[2 * k] | ((uint32_t)h[2 * k + 1] << 16);
}

// A1 from x; two elements per thread
__global__ void build_a1(const float* __restrict__ x, __hip_bfloat16* __restrict__ A1) {
  size_t t = (size_t)blockIdx.x * blockDim.x + threadIdx.x;
  if (t >= (size_t)NTOK * D_MODEL / 2) return;
  size_t n = t >> 9;
  size_t ip = (t & 511) * 2;
  float2 xv = *(const float2*)(x + n * D_MODEL + ip);
  unsigned short h[18];
  kan_feat_u(xv.x, h);
  kan_feat_u(xv.y, h + 9);
  uint32_t* dst = (uint32_t*)(A1 + n * (size_t)K1 + ip * NC);
#pragma unroll
  for (int k = 0; k < 9; ++k) dst[k] = (uint32_t)h[2 * k] | ((uint32_t)h[2 * k + 1] << 16);
}

// fallback only: h = Hc[:, :4096] * Hc[:, 4096:]; two j per thread
template <typename HT>
__global__ void glu_a3(const HT* __restrict__ Hc, __hip_bfloat16* __restrict__ A3c) {
  size_t t = (size_t)blockIdx.x * blockDim.x + threadIdx.x;
  if (t >= (size_t)CHUNK * D_FF / 2) return;
  size_t n = t >> 11;
  size_t jp = (t & 2047) * 2;
  float a0, a1, c0, c1;
  if constexpr (std::is_same<HT, float>::value) {
    float2 u = *(const float2*)(Hc + n * 8192 + jp);
    float2 v = *(const float2*)(Hc + n * 8192 + 4096 + jp);
    a0 = u.x; a1 = u.y; c0 = v.x; c1 = v.y;
  } else {
    a0 = __bfloat162float(Hc[n * 8192 + jp]);
    a1 = __bfloat162float(Hc[n * 8192 + jp + 1]);
    c0 = __bfloat162float(Hc[n * 8192 + 4096 + jp]);
    c1 = __bfloat162float(Hc[n * 8192 + 4096 + jp + 1]);
  }
  unsigned short h[18];
  kan_feat_u(a0 * c0, h);
  kan_feat_u(a1 * c1, h + 9);
  uint32_t* dst = (uint32_t*)(A3c + n * (size_t)K3 + jp * NC);
#pragma unroll
  for (int k = 0; k < 9; ++k) dst[k] = (uint32_t)h[2 * k] | ((uint32_t)h[2 * k + 1] << 16);
}

// ---------------------------------------------------------------------------
// 256x256 bf16 GEMM, BK=64, ring-2. C = A (M x K, rm) * Bw^T (Bw: N x K, rm).
// Staging per tile: 8 sites x (512thr x 16B) = 64KB. Site s covers 64 rows.
// Per-lane: row = wid*8 + (lane>>3), source k-group (lane&7)^(lane>>3);
// LDS dest linear (wave base + lane*16) => physical gp = gl ^ (row&7).
// ---------------------------------------------------------------------------
#define STAGE(Ts)                                                                        \
  {                                                                                      \
    const int _sl = ((Ts) & 1) * SLOT;                                                   \
    const size_t _ko = (size_t)(Ts) * 128;                                               \
    _Pragma("unroll") for (int _st = 0; _st < 4; ++_st) {                                \
      __builtin_amdgcn_global_load_lds(                                                  \
          (const __attribute__((address_space(1))) void*)(gA0 + _st * strideK + _ko),    \
          (__attribute__((address_space(3))) void*)(lds_raw + _sl + _st * 8192 + dW),    \
          16, 0, 0);                                                                     \
      __builtin_amdgcn_global_load_lds(                                                  \
          (const __attribute__((address_space(1))) void*)(gB0 + _st * strideK + _ko),    \
          (__attribute__((address_space(3))) void*)(lds_raw + _sl + 32768 +              \
                                                    _st * 8192 + dW),                    \
          16, 0, 0);                                                                     \
    }                                                                                    \
  }

template <typename CT, bool FUSE>
__global__ __launch_bounds__(512, 2) void gemm256(
    const __hip_bfloat16* __restrict__ A, const __hip_bfloat16* __restrict__ Bw,
    CT* __restrict__ Cp, int N, int K, int kLen,
    __hip_bfloat16* __restrict__ A3out) {
  __shared__ __align__(16) char lds_raw[2 * SLOT];  // 128 KB

  const int tid = threadIdx.x;
  const int wid = tid >> 6, lane = tid & 63;
  const int wr = wid >> 2, wc = wid & 3;  // 2M x 4N waves, 128x64 tiles

  // bijective XCD swizzle (T1); all grids have nwg % 8 == 0
  const int nwg = gridDim.x * gridDim.y;
  const int orig = blockIdx.y * gridDim.x + blockIdx.x;
  const int q = nwg >> 3, r = nwg & 7;
  const int xcd = orig & 7, lid = orig >> 3;
  const int wg = (xcd < r ? xcd * (q + 1) : r * (q + 1) + (xcd - r) * q) + lid;
  const int bx = wg % gridDim.x, by = wg / gridDim.x;

  const size_t brow = (size_t)by * 256;
  const size_t bcol = (size_t)bx * 256;
  const int kStart = (int)blockIdx.z * kLen;
  const int NT = kLen / 64;

  // staging addressing
  const int kbx = (lane & 7) ^ (lane >> 3);  // source 16B-group within 128B row
  const int rsub = lane >> 3;                // row within 8-row wave stripe
  const size_t strideK = (size_t)K * 128;    // 64 rows * K * 2B
  const char* gA0 = (const char*)A +
      ((brow + (size_t)(wid * 8 + rsub)) * (size_t)K + kStart + kbx * 8) * 2;
  const char* gB0 = (const char*)Bw +
      ((bcol + (size_t)(wid * 8 + rsub)) * (size_t)K + kStart + kbx * 8) * 2;
  const int dW = wid * 1024;

  // frag read offsets: row*128 + ((s*4 + (lane>>4)) ^ (lane&7)) * 16
  const int gx0 = (((lane >> 4) ^ (lane & 7))) * 16;
  const int gx1 = ((((lane >> 4) + 4) ^ (lane & 7))) * 16;
  const int arow = (wr * 128 + (lane & 15)) * 128;
  const int brw = 32768 + (wc * 64 + (lane & 15)) * 128;

  f32x4 acc[8][4] = {};

  // prologue: stage tile 0, drain, barrier
  STAGE(0);
  asm volatile("s_waitcnt vmcnt(0)" ::: "memory");
  __builtin_amdgcn_s_barrier();

  for (int T = 0; T < NT; ++T) {
    if (T + 1 < NT) STAGE(T + 1);

    const int sl = (T & 1) * SLOT;
    bf16x8 af[8], bfr[4];
    // ---- K-half 0
#pragma unroll
    for (int mf = 0; mf < 8; ++mf)
      af[mf] = *(const bf16x8*)(lds_raw + sl + arow + mf * 2048 + gx0);
#pragma unroll
    for (int nf = 0; nf < 4; ++nf)
      bfr[nf] = *(const bf16x8*)(lds_raw + sl + brw + nf * 2048 + gx0);
    __builtin_amdgcn_s_setprio(1);
#pragma unroll
    for (int mf = 0; mf < 8; ++mf)
#pragma unroll
      for (int nf = 0; nf < 4; ++nf)
        acc[mf][nf] =
            __builtin_amdgcn_mfma_f32_16x16x32_bf16(af[mf], bfr[nf], acc[mf][nf], 0, 0, 0);
    __builtin_amdgcn_s_setprio(0);
    // ---- K-half 1
#pragma unroll
    for (int mf = 0; mf < 8; ++mf)
      af[mf] = *(const bf16x8*)(lds_raw + sl + arow + mf * 2048 + gx1);
#pragma unroll
    for (int nf = 0; nf < 4; ++nf)
      bfr[nf] = *(const bf16x8*)(lds_raw + sl + brw + nf * 2048 + gx1);
    __builtin_amdgcn_s_setprio(1);
#pragma unroll
    for (int mf = 0; mf < 8; ++mf)
#pragma unroll
      for (int nf = 0; nf < 4; ++nf)
        acc[mf][nf] =
            __builtin_amdgcn_mfma_f32_16x16x32_bf16(af[mf], bfr[nf], acc[mf][nf], 0, 0, 0);
    __builtin_amdgcn_s_setprio(0);

    // one drain + barrier per K-64 tile (stage was issued a full tile ago)
    asm volatile("s_waitcnt vmcnt(0)" ::: "memory");
    asm volatile("s_waitcnt lgkmcnt(0)" ::: "memory");
    __builtin_amdgcn_s_barrier();
  }

  if constexpr (FUSE) {
    // ---- GLU + KAN-feature epilogue -> A3 (interleaved cols: 2p=w1, 2p+1=w2)
    float* gbuf = (float*)lds_raw;  // 16 slices x 16 rows x 128 pairs f32 = 128KB
#pragma unroll
    for (int mf = 0; mf < 8; ++mf) {
      const int s = wr * 8 + mf;
#pragma unroll
      for (int nf = 0; nf < 4; ++nf) {
#pragma unroll
        for (int rr = 0; rr < 4; ++rr) {
          float v = acc[mf][nf][rr];
          float w = __shfl_xor(v, 1, 64);
          if (!(lane & 1)) {
            const int r4 = (lane >> 4) * 4 + rr;
            const int ploc = wc * 32 + nf * 8 + ((lane & 14) >> 1);
            gbuf[s * 2048 + r4 * 128 + ploc] = v * w;
          }
        }
      }
    }
    __builtin_amdgcn_s_barrier();
    const int p2 = tid & 63;   // pair-pair index (handles pairs 2p2, 2p2+1)
    const int rb = tid >> 6;   // base row
    for (int k = 0; k < 32; ++k) {
      const int rr_ = rb + 8 * k;  // 0..255
      const int s = rr_ >> 4, rl = rr_ & 15;
      float g0 = gbuf[s * 2048 + rl * 128 + 2 * p2];
      float g1 = gbuf[s * 2048 + rl * 128 + 2 * p2 + 1];
      unsigned short h[18];
      kan_feat_u(g0, h);
      kan_feat_u(g1, h + 9);
      const size_t n = brow + rr_;
      const size_t pg = (bcol >> 1) + 2 * p2;
      uint32_t* dst = (uint32_t*)(A3out + n * (size_t)K3 + pg * NC);
#pragma unroll
      for (int qq = 0; qq < 9; ++qq)
        dst[qq] = (uint32_t)h[2 * qq] | ((uint32_t)h[2 * qq + 1] << 16);
    }
  } else {
    // plain epilogue: C/D layout col=lane&15, row=(lane>>4)*4+r
#pragma unroll
    for (int mf = 0; mf < 8; ++mf)
#pragma unroll
      for (int nf = 0; nf < 4; ++nf) {
        const size_t r0 = brow + wr * 128 + mf * 16 + (lane >> 4) * 4;
        const size_t c0 = bcol + wc * 64 + nf * 16 + (lane & 15);
        const size_t M = (size_t)gridDim.y * 256;
        CT* C = Cp + (size_t)blockIdx.z * M * (size_t)N;
#pragma unroll
        for (int rr = 0; rr < 4; ++rr) {
          float v = acc[mf][nf][rr];
          if constexpr (std::is_same<CT, float>::value)
            C[(r0 + rr) * (size_t)N + c0] = v;
          else
            C[(r0 + rr) * (size_t)N + c0] = __float2bfloat16(v);
        }
      }
  }
}

// sum nslice split-K partials (float4-vectorized)
__global__ void reduceK(const float* __restrict__ P, float* __restrict__ out,
                        size_t quarter, int nslice) {
  size_t t = (size_t)blockIdx.x * blockDim.x + threadIdx.x;
  if (t >= quarter) return;
  const float4* p = (const float4*)P;
  float4 a = p[t];
  for (int s = 1; s < nslice; ++s) {
    float4 b = p[(size_t)s * quarter + t];
    a.x += b.x; a.y += b.y; a.z += b.z; a.w += b.w;
  }
  ((float4*)out)[t] = a;
}

// ---------------------------------------------------------------------------
extern "C" void kernel_launch(void* const* d_in, const int* in_sizes, int n_in,
                              void* d_out, int out_size, void* d_ws, size_t ws_size,
                              hipStream_t stream) {
  const float* x   = (const float*)d_in[0];
  const float* bw1 = (const float*)d_in[1];
  const float* sw1 = (const float*)d_in[2];
  const float* bw2 = (const float*)d_in[3];
  const float* sw2 = (const float*)d_in[4];
  const float* bw3 = (const float*)d_in[5];
  const float* sw3 = (const float*)d_in[6];
  float* out = (float*)d_out;
  char* ws = (char*)d_ws;

  const size_t W12_B  = (size_t)8192 * K1 * 2;   // 150,994,944
  const size_t A1_B   = (size_t)NTOK * K1 * 2;   //  75,497,472
  const size_t A3F_B  = (size_t)NTOK * K3 * 2;   // 301,989,888
  const size_t A3C_B  = (size_t)CHUNK * K3 * 2;  //  75,497,472
  const size_t HF32_B = (size_t)NTOK * 8192 * 4; // 134,217,728

  const bool fused = ws_size >= W12_B + A1_B + A3F_B;  // 528,482,304
  const bool hF32  = ws_size >= W12_B + A1_B + HF32_B; // 360,710,144 (fallback)

  __hip_bfloat16* W12 = (__hip_bfloat16*)(ws);
  __hip_bfloat16* A1  = (__hip_bfloat16*)(ws + W12_B);
  __hip_bfloat16* W3  = A1;  // A1 dead after GEMM1

  size_t pairs12 = (size_t)D_FF * D_MODEL / 2;
  int blocks12 = (int)((pairs12 + 255) / 256);
  size_t pairs3 = (size_t)D_MODEL * D_FF / 2;
  int blocks3 = (int)((pairs3 + 255) / 256);
  size_t pairsA1 = (size_t)NTOK * D_MODEL / 2;

  if (fused) {
    __hip_bfloat16* A3f = (__hip_bfloat16*)(ws + W12_B + A1_B);
    float*          Par = (float*)(ws);  // reuses W12 region after GEMM1

    pack_kan_w<<<blocks12, 256, 0, stream>>>(bw1, sw1, W12, K1, 10, 2, 0, pairs12);
    pack_kan_w<<<blocks12, 256, 0, stream>>>(bw2, sw2, W12, K1, 10, 2, 1, pairs12);
    build_a1<<<(int)((pairsA1 + 255) / 256), 256, 0, stream>>>(x, A1);
    gemm256<float, true><<<dim3(8192 / 256, NTOK / 256, 1), 512, 0, stream>>>(
        A1, W12, nullptr, 8192, K1, K1, A3f);
    pack_kan_w<<<blocks3, 256, 0, stream>>>(bw3, sw3, W3, K3, 12, 1, 0, pairs3);
    gemm256<float, false><<<dim3(D_MODEL / 256, NTOK / 256, SPLITKF), 512, 0, stream>>>(
        A3f, W3, Par, D_MODEL, K3, K3 / SPLITKF, nullptr);
    size_t quarter = (size_t)NTOK * D_MODEL / 4;
    reduceK<<<(int)((quarter + 255) / 256), 256, 0, stream>>>(Par, out, quarter, SPLITKF);
  } else {
    void*           Hv  = (void*)(ws + W12_B + A1_B);
    __hip_bfloat16* A3c = (__hip_bfloat16*)(ws);        // W12 dead after GEMM1
    float*          Par = (float*)(ws + A3C_B);

    pack_kan_w<<<blocks12, 256, 0, stream>>>(bw1, sw1, W12, K1, 10, 1, 0, pairs12);
    pack_kan_w<<<blocks12, 256, 0, stream>>>(bw2, sw2, W12, K1, 10, 1, 4096, pairs12);
    build_a1<<<(int)((pairsA1 + 255) / 256), 256, 0, stream>>>(x, A1);
    if (hF32)
      gemm256<float, false><<<dim3(8192 / 256, NTOK / 256, 1), 512, 0, stream>>>(
          A1, W12, (float*)Hv, 8192, K1, K1, nullptr);
    else
      gemm256<__hip_bfloat16, false><<<dim3(8192 / 256, NTOK / 256, 1), 512, 0, stream>>>(
          A1, W12, (__hip_bfloat16*)Hv, 8192, K1, K1, nullptr);
    pack_kan_w<<<blocks3, 256, 0, stream>>>(bw3, sw3, W3, K3, 12, 1, 0, pairs3);
    for (int c = 0; c < NTOK / CHUNK; ++c) {
      size_t pairsG = (size_t)CHUNK * D_FF / 2;
      int blocksG = (int)((pairsG + 255) / 256);
      if (hF32)
        glu_a3<float><<<blocksG, 256, 0, stream>>>(
            (const float*)Hv + (size_t)c * CHUNK * 8192, A3c);
      else
        glu_a3<__hip_bfloat16><<<blocksG, 256, 0, stream>>>(
            (const __hip_bfloat16*)Hv + (size_t)c * CHUNK * 8192, A3c);
      gemm256<float, false><<<dim3(D_MODEL / 256, CHUNK / 256, SPLITK2), 512, 0, stream>>>(
          A3c, W3, Par, D_MODEL, K3, K3 / SPLITK2, nullptr);
      size_t quarter = (size_t)CHUNK * D_MODEL / 4;
      reduceK<<<(int)((quarter + 255) / 256), 256, 0, stream>>>(
          Par, out + (size_t)c * CHUNK * D_MODEL, quarter, SPLITK2);
    }
  }
}